// Round 7
// baseline (235.302 us; speedup 1.0000x reference)
//
#include <hip/hip_runtime.h>

#define TLEN 512
#define HID  64

typedef _Float16 half8 __attribute__((ext_vector_type(8)));
typedef float    f32x4 __attribute__((ext_vector_type(4)));

__device__ __forceinline__ float rcp_fast(float x) { return __builtin_amdgcn_rcpf(x); }
__device__ __forceinline__ float sigmoid_fast(float x) { return rcp_fast(1.0f + __expf(-x)); }
__device__ __forceinline__ float tanh_fast(float x) { return 1.0f - 2.0f * rcp_fast(__expf(2.0f * x) + 1.0f); }

// R7: 512 blocks x 4 waves (256 thr); block owns 4 batch rows -> TWO
// independent blocks per CU so barrier stalls of one overlap compute of the
// other (R6: one 8-wave block/CU, all waves on the same barrier = 35% dead).
// Wave w owns units [16w,16w+16) as 4 A-tiles; row-permuted W_hh so C/D
// (col=lane&15=batch, row=(lane>>4)*4+reg) gives all 4 gates of one
// (batch,unit) in one lane's acc regs. Batch cols c,c+4,c+8,c+12 duplicate:
// B-frags read hbuf[L&3] (4-lane broadcast, conflict-free) and each lane
// writes h ONCE -- kills R6's 8-way-conflict pattern (8.4M SQ_LDS_BANK_CONFLICT).
__global__ __launch_bounds__(256) __attribute__((amdgpu_waves_per_eu(2, 2)))
void lstm_mfma4(const float* __restrict__ x,
                const float* __restrict__ W_ih,
                const float* __restrict__ W_hh,
                const float* __restrict__ b_ih,
                const float* __restrict__ b_hh,
                const float* __restrict__ W_d,
                const float* __restrict__ b_d,
                float* __restrict__ out) {
    __shared__ __align__(16) float    xs[4][516];     // 4 x rows
    __shared__ __align__(16) _Float16 hbuf[2][4][72]; // ping-pong h, 4 real rows only

    const int tid = threadIdx.x;
    const int L   = tid & 63;
    const int w   = tid >> 6;        // wave 0..3, owns units [16w, 16w+16)
    const int r0  = blockIdx.x * 4;

    // ---- stage x rows (float4) ----
    for (int i = tid; i < 4 * 128; i += 256) {
        const int r = i >> 7, t4 = (i & 127) * 4;
        *(float4*)&xs[r][t4] = *(const float4*)&x[(size_t)(r0 + r) * TLEN + t4];
    }
    // ---- zero both h buffers (h0 = 0) ----
    for (int i = tid; i < 2 * 4 * 72; i += 256)
        ((_Float16*)hbuf)[i] = (_Float16)0.0f;

    // ---- resident A-frags: A[m][k], m=L&15, k=32q+(L>>4)*8+i ----
    // perm: tile tt -> unit 16w+4tt+(m>>2), gate m&3 (i,f,g,o)
    half8 af[4][2];
    {
        const int m = L & 15;
        const int g = m & 3;
        const int kb = (L >> 4) * 8;
#pragma unroll
        for (int tt = 0; tt < 4; ++tt) {
            const int uu = 16 * w + 4 * tt + (m >> 2);
            const float* row = &W_hh[(size_t)(g * HID + uu) * HID];
#pragma unroll
            for (int q = 0; q < 2; ++q) {
                const float* p = row + 32 * q + kb;
                half8 hf;
#pragma unroll
                for (int i = 0; i < 8; ++i) hf[i] = (_Float16)p[i];
                af[tt][q] = hf;
            }
        }
    }

    // ---- lane role: batch b = L&3 (== col&3), acc-select sel, unit u ----
    const int b   = L & 3;
    const int sel = (L >> 2) & 3;
    const int u   = 16 * w + 4 * sel + (L >> 4);

    float wih[4], bias[4];
#pragma unroll
    for (int g = 0; g < 4; ++g) {
        wih[g]  = W_ih[g * HID + u];
        bias[g] = b_ih[g * HID + u] + b_hh[g * HID + u];
    }

    const float* xrow = &xs[b][0];
    const int koff = (L >> 4) * 8;
    const _Float16* h0r = &hbuf[0][b][0];
    _Float16*       h0w = &hbuf[0][b][0];
    const _Float16* h1r = &hbuf[1][b][0];
    _Float16*       h1w = &hbuf[1][b][0];
    const f32x4 zero = {0.0f, 0.0f, 0.0f, 0.0f};
    float cst = 0.0f;

    __syncthreads();

    auto step = [&](const _Float16* hin, _Float16* hout, float xt) {
        half8 b0 = *(const half8*)(hin + koff);        // broadcast, conflict-free
        half8 b1 = *(const half8*)(hin + koff + 32);

        f32x4 d0 = __builtin_amdgcn_mfma_f32_16x16x32_f16(af[0][0], b0, zero, 0, 0, 0);
        f32x4 d1 = __builtin_amdgcn_mfma_f32_16x16x32_f16(af[1][0], b0, zero, 0, 0, 0);
        f32x4 d2 = __builtin_amdgcn_mfma_f32_16x16x32_f16(af[2][0], b0, zero, 0, 0, 0);
        f32x4 d3 = __builtin_amdgcn_mfma_f32_16x16x32_f16(af[3][0], b0, zero, 0, 0, 0);
        d0 = __builtin_amdgcn_mfma_f32_16x16x32_f16(af[0][1], b1, d0, 0, 0, 0);
        d1 = __builtin_amdgcn_mfma_f32_16x16x32_f16(af[1][1], b1, d1, 0, 0, 0);
        d2 = __builtin_amdgcn_mfma_f32_16x16x32_f16(af[2][1], b1, d2, 0, 0, 0);
        d3 = __builtin_amdgcn_mfma_f32_16x16x32_f16(af[3][1], b1, d3, 0, 0, 0);

        const f32x4 d = sel == 0 ? d0 : (sel == 1 ? d1 : (sel == 2 ? d2 : d3));

        const float ai  = d[0] + fmaf(xt, wih[0], bias[0]);
        const float afv = d[1] + fmaf(xt, wih[1], bias[1]);
        const float ag  = d[2] + fmaf(xt, wih[2], bias[2]);
        const float ao  = d[3] + fmaf(xt, wih[3], bias[3]);
        const float gi = sigmoid_fast(ai);
        const float gf = sigmoid_fast(afv);
        const float gg = tanh_fast(ag);
        const float go = sigmoid_fast(ao);
        cst = fmaf(gf, cst, gi * gg);
        const float hv = go * tanh_fast(cst);
        hout[u] = (_Float16)hv;     // single write per lane
    };

    for (int t = 0; t < TLEN; t += 2) {
        step(h0r, h1w, xrow[t]);
        __syncthreads();
        step(h1r, h0w, xrow[t + 1]);
        __syncthreads();
    }

    // ---- epilogue: wave w reduces batch row w (final h is in hbuf[0]) ----
    float pv = (float)hbuf[0][w][L] * W_d[L];
#pragma unroll
    for (int off = 32; off > 0; off >>= 1)
        pv += __shfl_xor(pv, off, 64);
    if (L == 0)
        out[r0 + w] = pv + b_d[0];
}

extern "C" void kernel_launch(void* const* d_in, const int* in_sizes, int n_in,
                              void* d_out, int out_size, void* d_ws, size_t ws_size,
                              hipStream_t stream) {
    const float* x    = (const float*)d_in[0];
    const float* W_ih = (const float*)d_in[1];
    const float* W_hh = (const float*)d_in[2];
    const float* b_ih = (const float*)d_in[3];
    const float* b_hh = (const float*)d_in[4];
    const float* W_d  = (const float*)d_in[5];
    const float* b_d  = (const float*)d_in[6];
    float* out = (float*)d_out;

    dim3 grid(512);    // 2048 / 4 batch rows per block -> 2 blocks per CU
    dim3 block(256);   // 4 waves
    lstm_mfma4<<<grid, block, 0, stream>>>(x, W_ih, W_hh, b_ih, b_hh, W_d, b_d, out);
}